// Round 18
// baseline (3723.829 us; speedup 1.0000x reference)
//
#include <hip/hip_runtime.h>
#include <math.h>

#define B_SZ 32
#define T_SZ 2048
#define DIN 256
#define DH 256
#define FOUR_D 1024

// scan: 8 WGs per batch, 512 threads (R16/R17 skeleton)
// thread -> (dd = tid>>4, gate = (tid>>2)&3, seg = tid&3)
#define NW 8
#define DPW 32
#define NSLOT 128      // u64 h-slots per batch (2 f16 dims + tag32 each)

// padded f16 h index: +8 f16 (16B) per 64-elem block
#define IK16(k) ((k) + ((k) >> 6) * 8)
// u_lds row stride in f16 elems (264*2=528B -> bank shift 4/row)
#define USTR 264

typedef _Float16 f16x2 __attribute__((ext_vector_type(2)));

#if __has_builtin(__builtin_amdgcn_fdot2)
#define FDOT2(a, b, c) __builtin_amdgcn_fdot2((a), (b), (c), false)
#else
__device__ __forceinline__ float fdot2_emu(f16x2 a, f16x2 b, float c) {
    return c + (float)a[0] * (float)b[0] + (float)a[1] * (float)b[1];
}
#define FDOT2(a, b, c) fdot2_emu((a), (b), (c))
#endif

__device__ __forceinline__ f16x2 H2(float f) {
    union { float f; f16x2 h; } u; u.f = f; return u.h;
}
__device__ __forceinline__ unsigned short F16B(float f) {
    union { _Float16 h; unsigned short u; } cu; cu.h = (_Float16)f; return cu.u;
}

__global__ void zero_ws(unsigned int* p, int n) {
    int i = blockIdx.x * blockDim.x + threadIdx.x;
    if (i < n) p[i] = 0u;
}

// px[r][f] = bias[f] + sum_k x_row(r)[k] * W[k][f];  r = tt*32 + b   (proven)
__global__ __launch_bounds__(256) void px_gemm(
    const float* __restrict__ x, const float* __restrict__ W,
    const float* __restrict__ bias, float* __restrict__ px,
    int t0)
{
    __shared__ float xt[16][DIN];
    const int tid = threadIdx.x;
    const int rbase = blockIdx.x * 16;

    {
        int row = tid >> 4;
        int seg = (tid & 15) * 16;
        int r = rbase + row;
        int bb = r & 31;
        int tt = r >> 5;
        const float4* s4 = (const float4*)(x + ((size_t)bb * T_SZ + (size_t)(t0 + tt)) * DIN + seg);
        float4* dst = (float4*)&xt[row][seg];
        dst[0] = s4[0]; dst[1] = s4[1]; dst[2] = s4[2]; dst[3] = s4[3];
    }
    __syncthreads();

    const int j = tid * 4;
    float4 bv = *(const float4*)&bias[j];
    float acc[16][4];
#pragma unroll
    for (int r = 0; r < 16; ++r) {
        acc[r][0] = bv.x; acc[r][1] = bv.y; acc[r][2] = bv.z; acc[r][3] = bv.w;
    }

    for (int k = 0; k < DIN; k += 4) {
        float4 w0 = *(const float4*)&W[(size_t)(k + 0) * FOUR_D + j];
        float4 w1 = *(const float4*)&W[(size_t)(k + 1) * FOUR_D + j];
        float4 w2 = *(const float4*)&W[(size_t)(k + 2) * FOUR_D + j];
        float4 w3 = *(const float4*)&W[(size_t)(k + 3) * FOUR_D + j];
#pragma unroll
        for (int r = 0; r < 16; ++r) {
            float4 xv = *(const float4*)&xt[r][k];
            acc[r][0] += xv.x * w0.x + xv.y * w1.x + xv.z * w2.x + xv.w * w3.x;
            acc[r][1] += xv.x * w0.y + xv.y * w1.y + xv.z * w2.y + xv.w * w3.y;
            acc[r][2] += xv.x * w0.z + xv.y * w1.z + xv.z * w2.z + xv.w * w3.z;
            acc[r][3] += xv.x * w0.w + xv.y * w1.w + xv.z * w2.w + xv.w * w3.w;
        }
    }

#pragma unroll
    for (int r = 0; r < 16; ++r) {
        float4 st = make_float4(acc[r][0], acc[r][1], acc[r][2], acc[r][3]);
        *(float4*)&px[((size_t)(rbase + r)) * FOUR_D + j] = st;
    }
}

// 16B poll load reaching the coherent point (R6-validated pattern): covers
// 2 self-tagged u64 slots; each u64 was written by ONE atomic store, so a
// torn 16B read can only mix whole slots, which per-slot tags catch.
__device__ __forceinline__ uint4 poll_load16(const unsigned long long* p) {
    uint4 r;
    asm volatile("global_load_dwordx4 %0, %1, off sc0 sc1\n\t"
                 "s_waitcnt vmcnt(0)"
                 : "=v"(r) : "v"(p) : "memory");
    return r;
}

// Single-barrier transposed scan (R17) + packed f16 exchange:
// slot j of batch b = [tag32 | h(2j+1) f16 | h(2j) f16], 128 slots/batch.
// Publishers pair via shfl_xor(hn,16); 64 pollers/WG spin one 16B load = 4
// dims each, bounded fallback to proven per-slot atomic spin.
__global__ __launch_bounds__(512, 2) void lstm_scan16(
    const float* __restrict__ px, const float* __restrict__ U,
    float* __restrict__ out, unsigned long long* __restrict__ hbuf,
    float* __restrict__ cstate, int t0, int ct)
{
    __shared__ _Float16 u_lds[128 * USTR];   // ~66 KB
    __shared__ _Float16 h1_lds[2][288];      // padded f16 h, parity dbuf

    const int b = blockIdx.x >> 3;     // batch (batch-contiguous)
    const int w = blockIdx.x & 7;      // WG-within-batch
    const int tid = threadIdx.x;
    const int dd = tid >> 4;           // dim within WG: 0..31
    const int gate = (tid >> 2) & 3;   // 0..3
    const int seg = tid & 3;           // K-segment: 0..3 (64 k each)
    const int colg = (gate << 8) + (w << 5) + dd;   // global preact column
    const int d = (w << 5) + dd;       // global dim of this 16-lane group
    const bool pub = (tid & 15) == 0;  // publisher lane for dim d

    // ---- prologue: stage U-slice to LDS as f16, conflict-free layout (R17)
    for (int it = 0; it < 64; ++it) {
        int lin = (it << 9) + tid;          // 0..32767
        int row = lin & 127;                // = dd*4 + gate
        int kk = lin >> 7;                  // 0..255
        int gcol = ((row & 3) << 8) + (w << 5) + (row >> 2);
        float v = U[(size_t)kk * FOUR_D + gcol];
        int sg = kk >> 6;                   // k-segment
        int cc = (kk >> 3) & 7;             // chunk within segment
        int jj = kk & 7;                    // elem within chunk
        int p = ((cc >> 1) << 3) + (sg << 1) + (cc & 1);
        u_lds[row * USTR + (p << 3) + jj] = (_Float16)v;
    }
    float c_reg = cstate[b * DH + d];
    __syncthreads();   // u_lds ready

    // ---- one-time: this thread's 8 U chunks -> pinned registers (from LDS)
    const int rowbase = (dd * 4 + gate) * USTR;
    float4 uq[8];
#pragma unroll
    for (int c2 = 0; c2 < 8; ++c2) {
        int p = ((c2 >> 1) << 3) + (seg << 1) + (c2 & 1);
        uq[c2] = *(const float4*)&u_lds[rowbase + (p << 3)];
    }
#pragma unroll
    for (int c2 = 0; c2 < 8; ++c2) {
        asm volatile("" : "+v"(uq[c2].x), "+v"(uq[c2].y),
                          "+v"(uq[c2].z), "+v"(uq[c2].w));
    }

    for (int tt = 0; tt < ct; ++tt) {
        const int s = t0 + tt + 1;     // computing h_s from h_{s-1}

        // px prefetch (independent of h): issue before the spin
        float pxv = px[((size_t)tt * B_SZ + b) * FOUR_D + colg];

        // acquire h_{s-1}: 64 pollers, one 16B load = 2 slots = 4 dims each.
        // Local dims (written by this WG's publishers) are skipped in steady
        // state; everything is polled/initialized at chunk start.
        if (tid < 64) {
            const bool local = (tid >> 3) == w;   // dims 4*tid.. in our 32?
            if (tt == 0 && t0 == 0) {
                *(unsigned long long*)&h1_lds[0][IK16(tid << 2)] = 0ull;
            } else if (tt == 0 || !local) {
                const unsigned want = (unsigned)(s - 1);
                const unsigned long long* slotp = hbuf +
                    ((size_t)((s - 1) & 1) * B_SZ + b) * NSLOT + (tid << 1);
                unsigned long long hh;
                int tries = 0;
                for (;;) {
                    uint4 v = poll_load16(slotp);
                    if (v.y == want && v.w == want) {
                        hh = (unsigned long long)v.x |
                             ((unsigned long long)v.z << 32);
                        break;
                    }
                    if (++tries > 64) {   // proven per-slot fallback (no hang)
                        unsigned long long q0, q1;
                        do { q0 = __hip_atomic_load(slotp, __ATOMIC_RELAXED,
                                                    __HIP_MEMORY_SCOPE_AGENT);
                        } while ((unsigned)(q0 >> 32) != want);
                        do { q1 = __hip_atomic_load(slotp + 1, __ATOMIC_RELAXED,
                                                    __HIP_MEMORY_SCOPE_AGENT);
                        } while ((unsigned)(q1 >> 32) != want);
                        hh = (q0 & 0xffffffffull) | (q1 << 32);
                        break;
                    }
                }
                *(unsigned long long*)&h1_lds[tt & 1][IK16(tid << 2)] = hh;
            }
        }
        __syncthreads();   // B1 (only barrier): h1_lds[tt&1] complete

        // GEMV: 8 chunks x { 1 padded b128 h read (broadcast) + 4 fdot2 },
        // U from pinned registers (R17)
        const _Float16* hrow = &h1_lds[tt & 1][seg * 72];
        float a0 = 0.f, a1 = 0.f, a2 = 0.f, a3 = 0.f;
#pragma unroll
        for (int c2 = 0; c2 < 8; ++c2) {
            float4 hv = *(const float4*)&hrow[c2 << 3];
            a0 = FDOT2(H2(uq[c2].x), H2(hv.x), a0);
            a1 = FDOT2(H2(uq[c2].y), H2(hv.y), a1);
            a2 = FDOT2(H2(uq[c2].z), H2(hv.z), a2);
            a3 = FDOT2(H2(uq[c2].w), H2(hv.w), a3);
        }
        float pr = (a0 + a1) + (a2 + a3);

        // seg butterfly: lanes ±1, ±2
        pr += __shfl_xor(pr, 1);
        pr += __shfl_xor(pr, 2);
        float pre = pxv + pr;

        // per-lane activation (gate 3 = tanh, else sigmoid)
        float act;
        if (gate < 3) {
            act = 1.0f / (1.0f + __expf(-pre));
        } else {
            float e = __expf(-2.0f * pre);
            act = 2.0f / (1.0f + e) - 1.0f;
        }

        // gate gather within the wave
        const int bl = (tid & 48) | seg;
        float ig = __shfl(act, bl);
        float fg = __shfl(act, bl | 4);
        float og = __shfl(act, bl | 8);
        float gv = __shfl(act, bl | 12);

        // cell update (16 lanes of dim d compute identically)
        float cn = fg * c_reg + ig * gv;
        c_reg = cn;
        float ec = __expf(-2.0f * cn);
        float hn = og * (2.0f / (1.0f + ec) - 1.0f);

        // pair exchange for packed publish: lane 0 <- lane 16, 32 <- 48
        float hn_n = __shfl_xor(hn, 16);

        if (pub) {
            if ((dd & 1) == 0) {
                // even-dim publisher: pack [tag | h_odd | h_even], one store
                unsigned long long pv =
                    ((unsigned long long)(unsigned)s << 32) |
                    ((unsigned)F16B(hn_n) << 16) | (unsigned)F16B(hn);
                __hip_atomic_store(
                    hbuf + ((size_t)(s & 1) * B_SZ + b) * NSLOT + (d >> 1),
                    pv, __ATOMIC_RELAXED, __HIP_MEMORY_SCOPE_AGENT);
            }
            h1_lds[(tt + 1) & 1][IK16(d)] = (_Float16)hn;   // local dim
            out[((size_t)b * T_SZ + (size_t)(s - 1)) * DH + d] = hn;
        }
        // single-barrier safety: same parity/rendezvous argument as R16/R17.
    }

    if (pub) cstate[b * DH + d] = c_reg;
}

extern "C" void kernel_launch(void* const* d_in, const int* in_sizes, int n_in,
                              void* d_out, int out_size, void* d_ws, size_t ws_size,
                              hipStream_t stream) {
    const float* x    = (const float*)d_in[0];
    const float* W    = (const float*)d_in[1];
    const float* U    = (const float*)d_in[2];
    const float* bias = (const float*)d_in[3];
    float* out = (float*)d_out;

    // ws layout: cstate 32KB @0 | hbuf 64KB @32K | pxbuf @160K
    float* cstate = (float*)d_ws;
    unsigned long long* hbuf = (unsigned long long*)((char*)d_ws + 32 * 1024);
    size_t px_off = 160 * 1024;
    float* pxbuf = (float*)((char*)d_ws + px_off);

    size_t avail = (ws_size > px_off) ? (ws_size - px_off) : 0;
    size_t per_step = (size_t)B_SZ * FOUR_D * sizeof(float);  // 128 KB
    long ct_max = (long)(avail / per_step);
    int CT = (ct_max >= T_SZ) ? T_SZ : (int)ct_max;
    if (CT < 1) CT = 1;

    // zero cstate + hbuf each launch
    int zero_words = (160 * 1024) / 4;
    zero_ws<<<(zero_words + 255) / 256, 256, 0, stream>>>((unsigned int*)d_ws, zero_words);

    for (int t0 = 0; t0 < T_SZ; t0 += CT) {
        int ct = (T_SZ - t0 < CT) ? (T_SZ - t0) : CT;
        int rows = ct * B_SZ;
        px_gemm<<<rows / 16, 256, 0, stream>>>(x, W, bias, pxbuf, t0);
        lstm_scan16<<<B_SZ * NW, 512, 0, stream>>>(pxbuf, U, out, hbuf, cstate, t0, ct);
    }
}

// Round 19
// 2987.677 us; speedup vs baseline: 1.2464x; 1.2464x over previous
//
#include <hip/hip_runtime.h>
#include <math.h>

#define B_SZ 32
#define T_SZ 2048
#define DIN 256
#define DH 256
#define FOUR_D 1024

// 8 WGs per batch, 512 threads (R16/R17 skeleton)
// thread -> (dd = tid>>4, gate = (tid>>2)&3, seg = tid&3)
#define NW 8
#define DPW 32

// padded f16 index: +8 f16 (16B) per 64-elem block
#define IK16(k) ((k) + ((k) >> 6) * 8)
// weight-LDS row stride in f16 elems (264*2=528B -> bank shift 4/row)
#define USTR 264

typedef _Float16 f16x2 __attribute__((ext_vector_type(2)));

#if __has_builtin(__builtin_amdgcn_fdot2)
#define FDOT2(a, b, c) __builtin_amdgcn_fdot2((a), (b), (c), false)
#else
__device__ __forceinline__ float fdot2_emu(f16x2 a, f16x2 b, float c) {
    return c + (float)a[0] * (float)b[0] + (float)a[1] * (float)b[1];
}
#define FDOT2(a, b, c) fdot2_emu((a), (b), (c))
#endif

__device__ __forceinline__ f16x2 H2(float f) {
    union { float f; f16x2 h; } u; u.f = f; return u.h;
}

__global__ void zero_ws(unsigned int* p, int n) {
    int i = blockIdx.x * blockDim.x + threadIdx.x;
    if (i < n) p[i] = 0u;
}

// Fully-fused single-launch LSTM (R17 scan + in-scan x.W):
//  - U-slice AND W-slice resident in LDS as f16 (derived conflict-free
//    layout: row = dd*4+gate stride 264; chunk p = (c>>1)*8 + seg*2 + (c&1)).
//  - U chunks additionally in pinned regs (R17-proven); W read from LDS in
//    the poll shadow (avoids R8's 16-quad scratch spill).
//  - x row staged f16 in LDS (IK16 layout), double-buffered, 2-deep prefetch.
//  - h exchange: R17-proven per-dim fp32 tagged agent-scope atomics.
//  - 1 barrier/step; cell state in registers for all T=2048; no px buffer.
__global__ __launch_bounds__(512, 2) void lstm_fused4(
    const float* __restrict__ x, const float* __restrict__ W,
    const float* __restrict__ U, const float* __restrict__ bias,
    float* __restrict__ out, unsigned long long* __restrict__ hbuf)
{
    __shared__ _Float16 u_lds[128 * USTR];   // 67.6 KB f16 U-slice
    __shared__ _Float16 w_lds[128 * USTR];   // 67.6 KB f16 W-slice
    __shared__ _Float16 h1_lds[2][288];      // padded f16 h, parity dbuf
    __shared__ _Float16 x_lds[2][288];       // padded f16 x row, parity dbuf

    const int b = blockIdx.x >> 3;     // batch (batch-contiguous)
    const int w = blockIdx.x & 7;      // WG-within-batch
    const int tid = threadIdx.x;
    const int dd = tid >> 4;           // dim within WG: 0..31
    const int gate = (tid >> 2) & 3;   // 0..3
    const int seg = tid & 3;           // K-segment: 0..3 (64 k each)
    const int colg = (gate << 8) + (w << 5) + dd;   // global preact column
    const int d = (w << 5) + dd;       // global dim of this 16-lane group
    const bool pub = (tid & 15) == 0;  // publisher lane for dim d

    // ---- prologue: stage U and W slices to LDS as f16 (derived layout)
    for (int it = 0; it < 64; ++it) {
        int lin = (it << 9) + tid;          // 0..32767
        int row = lin & 127;                // = dd*4 + gate
        int kk = lin >> 7;                  // 0..255
        int gcol = ((row & 3) << 8) + (w << 5) + (row >> 2);
        int sg = kk >> 6;
        int cc = (kk >> 3) & 7;
        int jj = kk & 7;
        int p = ((cc >> 1) << 3) + (sg << 1) + (cc & 1);
        int idx = row * USTR + (p << 3) + jj;
        u_lds[idx] = (_Float16)U[(size_t)kk * FOUR_D + gcol];
        w_lds[idx] = (_Float16)W[(size_t)kk * FOUR_D + gcol];
    }
    // x row 0 -> x_lds[0]; x row 1 -> prefetch regs
    float4 xr = make_float4(0.f, 0.f, 0.f, 0.f);
    if (tid < 64) {
        float4 v0 = *(const float4*)&x[((size_t)b * T_SZ) * DIN + tid * 4];
        _Float16* dst = &x_lds[0][IK16(tid * 4)];
        dst[0] = (_Float16)v0.x; dst[1] = (_Float16)v0.y;
        dst[2] = (_Float16)v0.z; dst[3] = (_Float16)v0.w;
        xr = *(const float4*)&x[((size_t)b * T_SZ + 1) * DIN + tid * 4];
    }
    const float binit = (seg == 0) ? bias[colg] : 0.0f;
    float c_reg = 0.0f;
    __syncthreads();   // u_lds / w_lds / x_lds[0] ready

    // ---- one-time: 8 U chunks -> pinned registers (from LDS, R17)
    const int rowb = (dd * 4 + gate) * USTR;
    float4 uq[8];
#pragma unroll
    for (int c2 = 0; c2 < 8; ++c2) {
        int p = ((c2 >> 1) << 3) + (seg << 1) + (c2 & 1);
        uq[c2] = *(const float4*)&u_lds[rowb + (p << 3)];
    }
#pragma unroll
    for (int c2 = 0; c2 < 8; ++c2) {
        asm volatile("" : "+v"(uq[c2].x), "+v"(uq[c2].y),
                          "+v"(uq[c2].z), "+v"(uq[c2].w));
    }

    for (int tt = 0; tt < T_SZ; ++tt) {
        // --- pre-poll: stash x_{tt+1} (regs->LDS), prefetch x_{tt+2}
        if (tid < 64) {
            if (tt + 1 < T_SZ) {
                _Float16* dst = &x_lds[(tt + 1) & 1][IK16(tid * 4)];
                dst[0] = (_Float16)xr.x; dst[1] = (_Float16)xr.y;
                dst[2] = (_Float16)xr.z; dst[3] = (_Float16)xr.w;
            }
            if (tt + 2 < T_SZ)
                xr = *(const float4*)&x[((size_t)b * T_SZ + tt + 2) * DIN + tid * 4];
        }

        // --- W-GEMV (h-independent; executes in the poll shadow)
        const _Float16* xrow = &x_lds[tt & 1][seg * 72];
        float a0 = binit, a1 = 0.f, a2 = 0.f, a3 = 0.f;
#pragma unroll
        for (int c2 = 0; c2 < 8; ++c2) {
            int p = ((c2 >> 1) << 3) + (seg << 1) + (c2 & 1);
            float4 wv = *(const float4*)&w_lds[rowb + (p << 3)];
            float4 xv = *(const float4*)&xrow[c2 << 3];
            a0 = FDOT2(H2(wv.x), H2(xv.x), a0);
            a1 = FDOT2(H2(wv.y), H2(xv.y), a1);
            a2 = FDOT2(H2(wv.z), H2(xv.z), a2);
            a3 = FDOT2(H2(wv.w), H2(xv.w), a3);
        }

        // --- acquire h_tt: threads 0..255 poll their own dim (tag == tt)
        if (tid < DH) {
            const bool local = (tid >> 5) == w;
            if (tt == 0) {
                h1_lds[0][IK16(tid)] = (_Float16)0.0f;
            } else if (!local) {
                const unsigned long long want = (unsigned long long)(unsigned)tt;
                const unsigned long long* slot = hbuf +
                    (((size_t)(tt & 1) * B_SZ + b) * DH + tid);
                unsigned long long v;
                do {
                    v = __hip_atomic_load(slot, __ATOMIC_RELAXED,
                                          __HIP_MEMORY_SCOPE_AGENT);
                } while ((v >> 32) != want);
                h1_lds[tt & 1][IK16(tid)] = (_Float16)__uint_as_float((unsigned)v);
            }
        }
        __syncthreads();   // B1 (only barrier): h1_lds[tt&1] + x stash done

        // --- U-GEMV from pinned registers (R17)
        const _Float16* hrow = &h1_lds[tt & 1][seg * 72];
#pragma unroll
        for (int c2 = 0; c2 < 8; ++c2) {
            float4 hv = *(const float4*)&hrow[c2 << 3];
            a0 = FDOT2(H2(uq[c2].x), H2(hv.x), a0);
            a1 = FDOT2(H2(uq[c2].y), H2(hv.y), a1);
            a2 = FDOT2(H2(uq[c2].z), H2(hv.z), a2);
            a3 = FDOT2(H2(uq[c2].w), H2(hv.w), a3);
        }
        float pr = (a0 + a1) + (a2 + a3);

        // seg butterfly: lanes ±1, ±2
        pr += __shfl_xor(pr, 1);
        pr += __shfl_xor(pr, 2);
        float pre = pr;

        // per-lane activation (gate 3 = tanh, else sigmoid)
        float act;
        if (gate < 3) {
            act = 1.0f / (1.0f + __expf(-pre));
        } else {
            float e = __expf(-2.0f * pre);
            act = 2.0f / (1.0f + e) - 1.0f;
        }

        // gate gather within the wave
        const int bl = (tid & 48) | seg;
        float ig = __shfl(act, bl);
        float fg = __shfl(act, bl | 4);
        float og = __shfl(act, bl | 8);
        float gv = __shfl(act, bl | 12);

        // cell update (16 lanes of dim d compute identically)
        float cn = fg * c_reg + ig * gv;
        c_reg = cn;
        float ec = __expf(-2.0f * cn);
        float hn = og * (2.0f / (1.0f + ec) - 1.0f);

        if (pub) {
            // publish FIRST (critical path), then local h_lds, then out
            unsigned long long pv =
                ((unsigned long long)(unsigned)(tt + 1) << 32) |
                (unsigned long long)__float_as_uint(hn);
            __hip_atomic_store(hbuf + (((size_t)((tt + 1) & 1) * B_SZ + b) * DH + d),
                               pv, __ATOMIC_RELAXED, __HIP_MEMORY_SCOPE_AGENT);
            h1_lds[(tt + 1) & 1][IK16(d)] = (_Float16)hn;   // local dim
            out[((size_t)b * T_SZ + tt) * DH + d] = hn;
        }
        // single-barrier safety (R16 argument), extended to x_lds:
        //  - x_lds[(tt+1)&1] written pre-B1_tt, read pre-B1_{tt+1}:  B1_tt orders.
        //  - x_lds[tt&1] read pre-B1_tt, next written pre-B1_{tt+1}: B1_tt orders.
        //  - h1_lds parity: identical to R16/R17.
    }
}

extern "C" void kernel_launch(void* const* d_in, const int* in_sizes, int n_in,
                              void* d_out, int out_size, void* d_ws, size_t ws_size,
                              hipStream_t stream) {
    const float* x    = (const float*)d_in[0];
    const float* W    = (const float*)d_in[1];
    const float* U    = (const float*)d_in[2];
    const float* bias = (const float*)d_in[3];
    float* out = (float*)d_out;

    // ws layout: hbuf 128KB @ 0 (tagged h, parity-double-buffered)
    unsigned long long* hbuf = (unsigned long long*)d_ws;

    // zero hbuf each launch (tags 1..2048 must start from a clean slate;
    // no state carried across calls)
    int zero_words = (128 * 1024) / 4;
    zero_ws<<<(zero_words + 255) / 256, 256, 0, stream>>>((unsigned int*)d_ws, zero_words);

    lstm_fused4<<<B_SZ * NW, 512, 0, stream>>>(x, W, U, bias, out, hbuf);
}

// Round 20
// 2954.038 us; speedup vs baseline: 1.2606x; 1.0114x over previous
//
#include <hip/hip_runtime.h>
#include <math.h>

#define B_SZ 32
#define T_SZ 2048
#define DIN 256
#define DH 256
#define FOUR_D 1024

// 8 WGs per batch, 512 threads (R16/R17 skeleton)
// thread -> (dd = tid>>4, gate = (tid>>2)&3, seg = tid&3)
#define NW 8
#define DPW 32

// padded f16 index: +8 f16 (16B) per 64-elem block
#define IK16(k) ((k) + ((k) >> 6) * 8)
// weight-LDS row stride in f16 elems (264*2=528B -> bank shift 4/row)
#define USTR 264

typedef _Float16 f16x2 __attribute__((ext_vector_type(2)));

#if __has_builtin(__builtin_amdgcn_fdot2)
#define FDOT2(a, b, c) __builtin_amdgcn_fdot2((a), (b), (c), false)
#else
__device__ __forceinline__ float fdot2_emu(f16x2 a, f16x2 b, float c) {
    return c + (float)a[0] * (float)b[0] + (float)a[1] * (float)b[1];
}
#define FDOT2(a, b, c) fdot2_emu((a), (b), (c))
#endif

__device__ __forceinline__ f16x2 H2(float f) {
    union { float f; f16x2 h; } u; u.f = f; return u.h;
}

__global__ void zero_ws(unsigned int* p, int n) {
    int i = blockIdx.x * blockDim.x + threadIdx.x;
    if (i < n) p[i] = 0u;
}

// Fully-fused single-launch LSTM (R19) with BOTH weight slices in pinned
// registers (uq + wq, 64 VGPRs). Per-step LDS traffic is pure broadcast
// (h row + x row) -> near-zero bank conflicts (R19's 1.36e8 were the
// per-lane-row W reads). w_lds/u_lds are prologue-only staging.
__global__ __launch_bounds__(512, 2) void lstm_fused5(
    const float* __restrict__ x, const float* __restrict__ W,
    const float* __restrict__ U, const float* __restrict__ bias,
    float* __restrict__ out, unsigned long long* __restrict__ hbuf)
{
    __shared__ _Float16 u_lds[128 * USTR];   // 67.6 KB f16 U-slice (staging)
    __shared__ _Float16 w_lds[128 * USTR];   // 67.6 KB f16 W-slice (staging)
    __shared__ _Float16 h1_lds[2][288];      // padded f16 h, parity dbuf
    __shared__ _Float16 x_lds[2][288];       // padded f16 x row, parity dbuf

    const int b = blockIdx.x >> 3;     // batch (batch-contiguous)
    const int w = blockIdx.x & 7;      // WG-within-batch
    const int tid = threadIdx.x;
    const int dd = tid >> 4;           // dim within WG: 0..31
    const int gate = (tid >> 2) & 3;   // 0..3
    const int seg = tid & 3;           // K-segment: 0..3 (64 k each)
    const int colg = (gate << 8) + (w << 5) + dd;   // global preact column
    const int d = (w << 5) + dd;       // global dim of this 16-lane group
    const bool pub = (tid & 15) == 0;  // publisher lane for dim d

    // ---- prologue: stage U and W slices to LDS as f16 (derived layout)
    for (int it = 0; it < 64; ++it) {
        int lin = (it << 9) + tid;          // 0..32767
        int row = lin & 127;                // = dd*4 + gate
        int kk = lin >> 7;                  // 0..255
        int gcol = ((row & 3) << 8) + (w << 5) + (row >> 2);
        int sg = kk >> 6;
        int cc = (kk >> 3) & 7;
        int jj = kk & 7;
        int p = ((cc >> 1) << 3) + (sg << 1) + (cc & 1);
        int idx = row * USTR + (p << 3) + jj;
        u_lds[idx] = (_Float16)U[(size_t)kk * FOUR_D + gcol];
        w_lds[idx] = (_Float16)W[(size_t)kk * FOUR_D + gcol];
    }
    // x row 0 -> x_lds[0]; x row 1 -> prefetch regs
    float4 xr = make_float4(0.f, 0.f, 0.f, 0.f);
    if (tid < 64) {
        float4 v0 = *(const float4*)&x[((size_t)b * T_SZ) * DIN + tid * 4];
        _Float16* dst = &x_lds[0][IK16(tid * 4)];
        dst[0] = (_Float16)v0.x; dst[1] = (_Float16)v0.y;
        dst[2] = (_Float16)v0.z; dst[3] = (_Float16)v0.w;
        xr = *(const float4*)&x[((size_t)b * T_SZ + 1) * DIN + tid * 4];
    }
    const float binit = (seg == 0) ? bias[colg] : 0.0f;
    float c_reg = 0.0f;
    __syncthreads();   // u_lds / w_lds / x_lds[0] ready

    // ---- one-time: 8 U chunks AND 8 W chunks -> pinned registers
    const int rowb = (dd * 4 + gate) * USTR;
    float4 uq[8], wq[8];
#pragma unroll
    for (int c2 = 0; c2 < 8; ++c2) {
        int p = ((c2 >> 1) << 3) + (seg << 1) + (c2 & 1);
        uq[c2] = *(const float4*)&u_lds[rowb + (p << 3)];
        wq[c2] = *(const float4*)&w_lds[rowb + (p << 3)];
    }
#pragma unroll
    for (int c2 = 0; c2 < 8; ++c2) {
        asm volatile("" : "+v"(uq[c2].x), "+v"(uq[c2].y),
                          "+v"(uq[c2].z), "+v"(uq[c2].w));
        asm volatile("" : "+v"(wq[c2].x), "+v"(wq[c2].y),
                          "+v"(wq[c2].z), "+v"(wq[c2].w));
    }

    for (int tt = 0; tt < T_SZ; ++tt) {
        // --- pre-poll: stash x_{tt+1} (regs->LDS), prefetch x_{tt+2}
        if (tid < 64) {
            if (tt + 1 < T_SZ) {
                _Float16* dst = &x_lds[(tt + 1) & 1][IK16(tid * 4)];
                dst[0] = (_Float16)xr.x; dst[1] = (_Float16)xr.y;
                dst[2] = (_Float16)xr.z; dst[3] = (_Float16)xr.w;
            }
            if (tt + 2 < T_SZ)
                xr = *(const float4*)&x[((size_t)b * T_SZ + tt + 2) * DIN + tid * 4];
        }

        // --- W-GEMV (h-independent; poll shadow); x via broadcast b128 reads
        const _Float16* xrow = &x_lds[tt & 1][seg * 72];
        float a0 = binit, a1 = 0.f, a2 = 0.f, a3 = 0.f;
#pragma unroll
        for (int c2 = 0; c2 < 8; ++c2) {
            float4 xv = *(const float4*)&xrow[c2 << 3];
            a0 = FDOT2(H2(wq[c2].x), H2(xv.x), a0);
            a1 = FDOT2(H2(wq[c2].y), H2(xv.y), a1);
            a2 = FDOT2(H2(wq[c2].z), H2(xv.z), a2);
            a3 = FDOT2(H2(wq[c2].w), H2(xv.w), a3);
        }

        // --- acquire h_tt: threads 0..255 poll their own dim (tag == tt)
        if (tid < DH) {
            const bool local = (tid >> 5) == w;
            if (tt == 0) {
                h1_lds[0][IK16(tid)] = (_Float16)0.0f;
            } else if (!local) {
                const unsigned long long want = (unsigned long long)(unsigned)tt;
                const unsigned long long* slot = hbuf +
                    (((size_t)(tt & 1) * B_SZ + b) * DH + tid);
                unsigned long long v;
                do {
                    v = __hip_atomic_load(slot, __ATOMIC_RELAXED,
                                          __HIP_MEMORY_SCOPE_AGENT);
                } while ((v >> 32) != want);
                h1_lds[tt & 1][IK16(tid)] = (_Float16)__uint_as_float((unsigned)v);
            }
        }
        __syncthreads();   // B1 (only barrier): h1_lds[tt&1] + x stash done

        // --- U-GEMV from pinned registers (R17); h via broadcast b128 reads
        const _Float16* hrow = &h1_lds[tt & 1][seg * 72];
#pragma unroll
        for (int c2 = 0; c2 < 8; ++c2) {
            float4 hv = *(const float4*)&hrow[c2 << 3];
            a0 = FDOT2(H2(uq[c2].x), H2(hv.x), a0);
            a1 = FDOT2(H2(uq[c2].y), H2(hv.y), a1);
            a2 = FDOT2(H2(uq[c2].z), H2(hv.z), a2);
            a3 = FDOT2(H2(uq[c2].w), H2(hv.w), a3);
        }
        float pr = (a0 + a1) + (a2 + a3);

        // seg butterfly: lanes ±1, ±2
        pr += __shfl_xor(pr, 1);
        pr += __shfl_xor(pr, 2);
        float pre = pr;

        // per-lane activation (gate 3 = tanh, else sigmoid)
        float act;
        if (gate < 3) {
            act = 1.0f / (1.0f + __expf(-pre));
        } else {
            float e = __expf(-2.0f * pre);
            act = 2.0f / (1.0f + e) - 1.0f;
        }

        // gate gather within the wave
        const int bl = (tid & 48) | seg;
        float ig = __shfl(act, bl);
        float fg = __shfl(act, bl | 4);
        float og = __shfl(act, bl | 8);
        float gv = __shfl(act, bl | 12);

        // cell update (16 lanes of dim d compute identically)
        float cn = fg * c_reg + ig * gv;
        c_reg = cn;
        float ec = __expf(-2.0f * cn);
        float hn = og * (2.0f / (1.0f + ec) - 1.0f);

        if (pub) {
            // publish FIRST (critical path), then local h_lds, then out
            unsigned long long pv =
                ((unsigned long long)(unsigned)(tt + 1) << 32) |
                (unsigned long long)__float_as_uint(hn);
            __hip_atomic_store(hbuf + (((size_t)((tt + 1) & 1) * B_SZ + b) * DH + d),
                               pv, __ATOMIC_RELAXED, __HIP_MEMORY_SCOPE_AGENT);
            h1_lds[(tt + 1) & 1][IK16(d)] = (_Float16)hn;   // local dim
            out[((size_t)b * T_SZ + tt) * DH + d] = hn;
        }
        // single-barrier safety (R16 argument), extended to x_lds:
        //  - x_lds[(tt+1)&1] written pre-B1_tt, read pre-B1_{tt+1}:  B1_tt orders.
        //  - x_lds[tt&1] read pre-B1_tt, next written pre-B1_{tt+1}: B1_tt orders.
        //  - h1_lds parity: identical to R16/R17.
    }
}

extern "C" void kernel_launch(void* const* d_in, const int* in_sizes, int n_in,
                              void* d_out, int out_size, void* d_ws, size_t ws_size,
                              hipStream_t stream) {
    const float* x    = (const float*)d_in[0];
    const float* W    = (const float*)d_in[1];
    const float* U    = (const float*)d_in[2];
    const float* bias = (const float*)d_in[3];
    float* out = (float*)d_out;

    // ws layout: hbuf 128KB @ 0 (tagged h, parity-double-buffered)
    unsigned long long* hbuf = (unsigned long long*)d_ws;

    // zero hbuf each launch (clean tags; no cross-call state)
    int zero_words = (128 * 1024) / 4;
    zero_ws<<<(zero_words + 255) / 256, 256, 0, stream>>>((unsigned int*)d_ws, zero_words);

    lstm_fused5<<<B_SZ * NW, 512, 0, stream>>>(x, W, U, bias, out, hbuf);
}